// Round 7
// baseline (239.718 us; speedup 1.0000x reference)
//
#include <hip/hip_runtime.h>

// Sizes (fixed by the problem)
#define BB 4
#define CC 256
#define HH 128
#define WW 128
#define HP 64          // pooled H, W
#define NP 4096        // HP*HP tokens per batch

#define L2E 1.4426950408889634f

typedef __attribute__((ext_vector_type(4)))  float f32x4;
typedef __attribute__((ext_vector_type(16))) float f32x16;
typedef __attribute__((ext_vector_type(8)))  short bf16x8;       // 8 bf16 in 4 VGPRs
typedef __attribute__((ext_vector_type(4)))  unsigned int u32x4;

// 2^x via v_exp_f32 (native). NOT __exp2f: that name collides with glibc macros.
static __device__ __forceinline__ float exp2fast(float x) {
    return __builtin_amdgcn_exp2f(x);
}

// float -> bf16 bits, round-to-nearest-even (finite inputs only)
static __device__ __forceinline__ unsigned short f2bf(float f) {
    unsigned int u = __float_as_uint(f);
    u = (u + 0x7FFFu + ((u >> 16) & 1u)) >> 16;
    return (unsigned short)u;
}
static __device__ __forceinline__ unsigned int pk2(float a, float b) {
    return (unsigned int)f2bf(a) | ((unsigned int)f2bf(b) << 16);
}

// ---------------------------------------------------------------------------
// K1: 2x2 average pool. x[b][c][128][128] -> xp[b][c][64*64]
// ---------------------------------------------------------------------------
__global__ __launch_bounds__(256) void pool_kernel(const float* __restrict__ x,
                                                   float* __restrict__ xp) {
    int tid = blockIdx.x * 256 + threadIdx.x;      // B*C*NP threads
    int wp = tid & 63;
    int hp = (tid >> 6) & 63;
    int bc = tid >> 12;
    const float* src = x + (size_t)bc * (HH * WW) + (2 * hp) * WW + 2 * wp;
    float2 a = *(const float2*)(src);
    float2 b = *(const float2*)(src + WW);
    xp[tid] = 0.25f * (a.x + a.y + b.x + b.y);
}

// ---------------------------------------------------------------------------
// K2: fused QKV projection GEMM (fp32 math), bf16 outputs in two layouts:
//   qk[b][n][64]  : o 0..31 = q (PRE-SCALED by log2(e)), 32..63 = k
//   vt[b][c][n]   : c 0..255                  (channel-major, for PV A frags)
// Q is scaled by log2(e) so flash softmax can use exp2 directly.
// ---------------------------------------------------------------------------
__global__ __launch_bounds__(256) void proj_kernel(const float* __restrict__ xp,
    const float* __restrict__ wq, const float* __restrict__ bq,
    const float* __restrict__ wk, const float* __restrict__ bk,
    const float* __restrict__ wv, const float* __restrict__ bv,
    unsigned short* __restrict__ qk, unsigned short* __restrict__ vt) {
    __shared__ float lx[32][64];    // [c][n]
    __shared__ float lwT[32][64];   // [c][o]
    int t = threadIdx.x;
    int ot = blockIdx.x % 5;
    int nt = (blockIdx.x / 5) & 63;
    int b  = blockIdx.x / 320;

    float acc[4][4];
    #pragma unroll
    for (int i = 0; i < 4; i++)
        #pragma unroll
        for (int j = 0; j < 4; j++) acc[i][j] = 0.f;

    int n0 = (t & 15) * 4;
    int o0 = (t >> 4) * 4;

    int o_l = t >> 2;               // 0..63 weight row
    int og  = ot * 64 + o_l;
    const float* wrow;
    if (og < 32)      wrow = wq + og * CC;
    else if (og < 64) wrow = wk + (og - 32) * CC;
    else              wrow = wv + (og - 64) * CC;
    int c8 = (t & 3) * 8;

    const float* xbase = xp + (size_t)b * CC * NP + nt * 64;
    int cl = t >> 3;                // 0..31
    int nl = (t & 7) * 8;

    for (int c0 = 0; c0 < 256; c0 += 32) {
        const float* xg = xbase + (size_t)(c0 + cl) * NP + nl;
        float4 v0 = *(const float4*)(xg);
        float4 v1 = *(const float4*)(xg + 4);
        float4 w0 = *(const float4*)(wrow + c0 + c8);
        float4 w1 = *(const float4*)(wrow + c0 + c8 + 4);
        __syncthreads();
        *(float4*)&lx[cl][nl]     = v0;
        *(float4*)&lx[cl][nl + 4] = v1;
        lwT[c8 + 0][o_l] = w0.x; lwT[c8 + 1][o_l] = w0.y;
        lwT[c8 + 2][o_l] = w0.z; lwT[c8 + 3][o_l] = w0.w;
        lwT[c8 + 4][o_l] = w1.x; lwT[c8 + 5][o_l] = w1.y;
        lwT[c8 + 6][o_l] = w1.z; lwT[c8 + 7][o_l] = w1.w;
        __syncthreads();
        #pragma unroll
        for (int cc = 0; cc < 32; cc += 4) {
            float4 xv[4], wv4[4];
            #pragma unroll
            for (int ci = 0; ci < 4; ci++) {
                xv[ci]  = *(const float4*)&lx[cc + ci][n0];
                wv4[ci] = *(const float4*)&lwT[cc + ci][o0];
            }
            #pragma unroll
            for (int ci = 0; ci < 4; ci++) {
                float xn[4] = {xv[ci].x, xv[ci].y, xv[ci].z, xv[ci].w};
                float wo[4] = {wv4[ci].x, wv4[ci].y, wv4[ci].z, wv4[ci].w};
                #pragma unroll
                for (int ni = 0; ni < 4; ni++)
                    #pragma unroll
                    for (int oi = 0; oi < 4; oi++)
                        acc[ni][oi] += xn[ni] * wo[oi];
            }
        }
    }

    float bias[4];
    #pragma unroll
    for (int oi = 0; oi < 4; oi++) {
        int o = ot * 64 + o0 + oi;
        bias[oi] = (o < 32) ? bq[o] : (o < 64) ? bk[o - 32] : bv[o - 64];
    }

    if (ot == 0) {
        float qs = (o0 < 32) ? L2E : 1.0f;   // q rows pre-scaled for exp2 softmax
        #pragma unroll
        for (int ni = 0; ni < 4; ni++) {
            ushort4 r;
            r.x = f2bf((acc[ni][0] + bias[0]) * qs);
            r.y = f2bf((acc[ni][1] + bias[1]) * qs);
            r.z = f2bf((acc[ni][2] + bias[2]) * qs);
            r.w = f2bf((acc[ni][3] + bias[3]) * qs);
            int n = nt * 64 + n0 + ni;
            *(ushort4*)(qk + ((size_t)b * NP + n) * 64 + o0) = r;
        }
    } else {
        #pragma unroll
        for (int oi = 0; oi < 4; oi++) {
            int c = ot * 64 + o0 + oi - 64;
            ushort4 r;
            r.x = f2bf(acc[0][oi] + bias[oi]);
            r.y = f2bf(acc[1][oi] + bias[oi]);
            r.z = f2bf(acc[2][oi] + bias[oi]);
            r.w = f2bf(acc[3][oi] + bias[oi]);
            *(ushort4*)(vt + ((size_t)b * CC + c) * NP + nt * 64 + n0) = r;
        }
    }
}

// ---------------------------------------------------------------------------
// K3: swapped-operand 32x32 MFMA flash attention, 2D wave split:
// 512-thread block = 8 waves; wave w: ch = w&1 (128 channels), ks = w>>1
// (1024 keys). acc = 4 x f32x16 = 64 regs -> launch_bounds(512,4) caps 128
// regs -> 4 waves/SIMD (2 blocks/CU). QK^T + softmax duplicated per channel
// half; energy already in log2 units (Q pre-scaled), softmax uses exp2.
// Split-K combine per channel group (3 sequential LDS rounds); ks==0 writes.
//
// QK^T (swapped): S^T = mfma_32x32x16(A=K, B=Q).
//   D layout (m74/m101): col=lane&31 = q; row=(r&3)+8*(r>>2)+4*(lane>>5) = key.
// PV: out[c][q] = mfma(A=V^T, B=P); A-frag 16B contiguous from vt[c][n];
//   P B-frag built in-register via pk2 + shfl_xor(32).
// ---------------------------------------------------------------------------
__global__ __launch_bounds__(512, 4) void flash32_kernel(const unsigned short* __restrict__ qk,
                                                         const unsigned short* __restrict__ vt,
                                                         float* __restrict__ att) {
    __shared__ float cacc[2][64][68];  // combine: per ch-group, 64 lanes x 64 f32 (16B-aligned rows)
    __shared__ float cml[2][64][2];    // combine: m, l per lane
    int t    = threadIdx.x;
    int lane = t & 63;
    int w    = t >> 6;                 // 0..7
    int ch   = w & 1;                  // channel half
    int ks   = w >> 1;                 // key quarter
    int j    = blockIdx.x;
    int b    = j & 3;                  // batch -> XCD pinning
    int qt   = j >> 2;                 // 0..127 q-tile (32 rows)

    const unsigned short* qkb = qk + (size_t)b * NP * 64;
    const unsigned short* vtb = vt + ((size_t)b * CC + ch * 128) * NP;

    int q  = lane & 31;
    int hi = lane >> 5;

    // Q B-frags: col=q, k=hi*8+e (ch 0-15) and +16 (ch 16-31); held whole kernel
    const unsigned short* qrow = qkb + (size_t)(qt * 32 + q) * 64;
    bf16x8 qf0 = *(const bf16x8*)(qrow + hi * 8);
    bf16x8 qf1 = *(const bf16x8*)(qrow + 16 + hi * 8);

    f32x16 acc[4];
    #pragma unroll
    for (int ct = 0; ct < 4; ct++)
        #pragma unroll
        for (int r = 0; r < 16; r++) acc[ct][r] = 0.f;
    float mrun = -3.0e38f, lrun = 0.f;

    const f32x16 z16 = {0.f,0.f,0.f,0.f,0.f,0.f,0.f,0.f,0.f,0.f,0.f,0.f,0.f,0.f,0.f,0.f};

    for (int kci = 0; kci < 32; ++kci) {
        int kbase = (ks * 32 + kci) * 32;

        // ---- QK^T swapped: A=K (row=key), B=Q -> S^T (log2 units)
        const unsigned short* krow = qkb + (size_t)(kbase + q) * 64 + 32;
        bf16x8 kf0 = *(const bf16x8*)(krow + hi * 8);
        bf16x8 kf1 = *(const bf16x8*)(krow + 16 + hi * 8);
        f32x16 s = __builtin_amdgcn_mfma_f32_32x32x16_bf16(kf0, qf0, z16, 0, 0, 0);
        s = __builtin_amdgcn_mfma_f32_32x32x16_bf16(kf1, qf1, s, 0, 0, 0);

        // ---- in-lane max over 16 keys + 1 cross-half swap
        float m01 = fmaxf(s[0], s[1]),   m23 = fmaxf(s[2], s[3]);
        float m45 = fmaxf(s[4], s[5]),   m67 = fmaxf(s[6], s[7]);
        float m89 = fmaxf(s[8], s[9]),   mab = fmaxf(s[10], s[11]);
        float mcd = fmaxf(s[12], s[13]), mef = fmaxf(s[14], s[15]);
        float mx = fmaxf(fmaxf(fmaxf(m01, m23), fmaxf(m45, m67)),
                         fmaxf(fmaxf(m89, mab), fmaxf(mcd, mef)));
        mx = fmaxf(mx, __shfl_xor(mx, 32, 64));

        // ---- defer-max (T13, log2 domain): rescale only when max grew by > ~11.5
        if (!__all(mx - mrun <= 11.5f)) {
            float mn = fmaxf(mrun, mx);
            float sc = exp2fast(mrun - mn);
            mrun = mn;
            lrun *= sc;
            #pragma unroll
            for (int ct = 0; ct < 4; ct++)
                #pragma unroll
                for (int r = 0; r < 16; r++) acc[ct][r] *= sc;
        }

        // ---- P = exp2(S^T - m): pack pairs as we go (saves regs)
        unsigned int pkr[8];
        float ss = 0.f;
        #pragma unroll
        for (int r2 = 0; r2 < 8; r2++) {
            float p0 = exp2fast(s[2 * r2]     - mrun);
            float p1 = exp2fast(s[2 * r2 + 1] - mrun);
            ss += p0 + p1;
            pkr[r2] = pk2(p0, p1);
        }
        ss += __shfl_xor(ss, 32, 64);
        lrun += ss;

        // ---- PV: per 16-key window, build P B-frag in-register, 4 c-tiles
        #pragma unroll
        for (int w2 = 0; w2 < 2; w2++) {
            unsigned int a0 = pkr[4 * w2 + 0];
            unsigned int a1 = pkr[4 * w2 + 1];
            unsigned int c0 = pkr[4 * w2 + 2];
            unsigned int c1 = pkr[4 * w2 + 3];
            unsigned int sa0 = __shfl_xor(a0, 32, 64);
            unsigned int sa1 = __shfl_xor(a1, 32, 64);
            unsigned int sc0 = __shfl_xor(c0, 32, 64);
            unsigned int sc1 = __shfl_xor(c1, 32, 64);
            u32x4 fr;
            if (hi == 0) { fr[0] = a0;  fr[1] = a1;  fr[2] = sa0; fr[3] = sa1; }
            else         { fr[0] = sc0; fr[1] = sc1; fr[2] = c0;  fr[3] = c1;  }
            bf16x8 pf = __builtin_bit_cast(bf16x8, fr);
            const unsigned short* vb = vtb + kbase + w2 * 16 + hi * 8;
            #pragma unroll
            for (int ct = 0; ct < 4; ct++) {
                bf16x8 vf = *(const bf16x8*)(vb + (size_t)(ct * 32 + q) * NP);
                acc[ct] = __builtin_amdgcn_mfma_f32_32x32x16_bf16(vf, pf, acc[ct], 0, 0, 0);
            }
        }
    }

    // ---- split-K combine within each channel group (ks 3,2,1 -> ks 0)
    for (int sIdx = 3; sIdx >= 1; --sIdx) {
        if (ks == sIdx) {
            #pragma unroll
            for (int ct = 0; ct < 4; ct++)
                #pragma unroll
                for (int rr = 0; rr < 4; rr++) {
                    float4 v4 = {acc[ct][rr*4+0], acc[ct][rr*4+1], acc[ct][rr*4+2], acc[ct][rr*4+3]};
                    *(float4*)&cacc[ch][lane][ct * 16 + rr * 4] = v4;
                }
            cml[ch][lane][0] = mrun; cml[ch][lane][1] = lrun;
        }
        __syncthreads();
        if (ks == 0) {
            float mo = cml[ch][lane][0];
            float lo = cml[ch][lane][1];
            float mn = fmaxf(mrun, mo);
            float e0 = exp2fast(mrun - mn);
            float e1 = exp2fast(mo - mn);
            mrun = mn;
            lrun = lrun * e0 + lo * e1;
            #pragma unroll
            for (int ct = 0; ct < 4; ct++)
                #pragma unroll
                for (int r = 0; r < 16; r++)
                    acc[ct][r] = acc[ct][r] * e0 + cacc[ch][lane][ct * 16 + r] * e1;
        }
        __syncthreads();
    }

    if (ks == 0) {
        float inv = 1.0f / lrun;
        #pragma unroll
        for (int ct = 0; ct < 4; ct++)
            #pragma unroll
            for (int r = 0; r < 16; r++) {
                int c = ch * 128 + ct * 32 + (r & 3) + 8 * (r >> 2) + 4 * hi;
                att[((size_t)b * CC + c) * NP + qt * 32 + q] = acc[ct][r] * inv;
            }
    }
}

// ---------------------------------------------------------------------------
// K4: bilinear x2 upsample (half-pixel, edge clamp) + gamma * up + x
// ---------------------------------------------------------------------------
__global__ __launch_bounds__(256) void upsample_kernel(const float* __restrict__ att,
                                                       const float* __restrict__ x,
                                                       const float* __restrict__ gamma,
                                                       float* __restrict__ out) {
    int tid = blockIdx.x * 256 + threadIdx.x;    // B*C*H*W
    int w = tid & 127;
    int h = (tid >> 7) & 127;
    int bc = tid >> 14;
    float g = gamma[0];
    float sh = 0.5f * h - 0.25f;
    float sw = 0.5f * w - 0.25f;
    float fhf = floorf(sh), fwf = floorf(sw);
    float th = sh - fhf, tw = sw - fwf;
    int ih = (int)fhf, iw = (int)fwf;
    int ih0 = ih < 0 ? 0 : ih;
    int ih1 = ih + 1 > 63 ? 63 : ih + 1;
    int iw0 = iw < 0 ? 0 : iw;
    int iw1 = iw + 1 > 63 ? 63 : iw + 1;
    const float* a = att + (size_t)bc * NP;
    float v00 = a[ih0 * 64 + iw0], v01 = a[ih0 * 64 + iw1];
    float v10 = a[ih1 * 64 + iw0], v11 = a[ih1 * 64 + iw1];
    float top = v00 + tw * (v01 - v00);
    float bot = v10 + tw * (v11 - v10);
    float up  = top + th * (bot - top);
    out[tid] = g * up + x[tid];
}

// ---------------------------------------------------------------------------
extern "C" void kernel_launch(void* const* d_in, const int* in_sizes, int n_in,
                              void* d_out, int out_size, void* d_ws, size_t ws_size,
                              hipStream_t stream) {
    (void)in_sizes; (void)n_in; (void)out_size; (void)ws_size;
    const float* x     = (const float*)d_in[0];
    const float* wq    = (const float*)d_in[1];
    const float* bq    = (const float*)d_in[2];
    const float* wk    = (const float*)d_in[3];
    const float* bk    = (const float*)d_in[4];
    const float* wv    = (const float*)d_in[5];
    const float* bv    = (const float*)d_in[6];
    const float* gamma = (const float*)d_in[7];
    float* out = (float*)d_out;
    float* ws  = (float*)d_ws;

    float*          xp  = ws;                                  // 4,194,304 f32 (16 MB)
    unsigned short* qkb = (unsigned short*)(ws + 4194304);     // 4*4096*64  bf16 (2 MB)
    unsigned short* vtb = qkb + 1048576;                       // 4*256*4096 bf16 (8 MB)
    float*          att = (float*)(vtb + 4194304);             // 4,194,304 f32 (16 MB)

    pool_kernel<<<16384, 256, 0, stream>>>(x, xp);
    proj_kernel<<<1280, 256, 0, stream>>>(xp, wq, bq, wk, bk, wv, bv, qkb, vtb);
    flash32_kernel<<<512, 512, 0, stream>>>(qkb, vtb, att);
    upsample_kernel<<<65536, 256, 0, stream>>>(att, x, gamma, out);
}

// Round 8
// 158.920 us; speedup vs baseline: 1.5084x; 1.5084x over previous
//
#include <hip/hip_runtime.h>

// Sizes (fixed by the problem)
#define BB 4
#define CC 256
#define HH 128
#define WW 128
#define HP 64          // pooled H, W
#define NP 4096        // HP*HP tokens per batch

#define L2E 1.4426950408889634f

typedef __attribute__((ext_vector_type(4)))  float f32x4;
typedef __attribute__((ext_vector_type(16))) float f32x16;
typedef __attribute__((ext_vector_type(8)))  short bf16x8;       // 8 bf16 in 4 VGPRs
typedef __attribute__((ext_vector_type(4)))  unsigned int u32x4;

// 2^x via v_exp_f32 (native). NOT __exp2f: that name collides with glibc macros.
static __device__ __forceinline__ float exp2fast(float x) {
    return __builtin_amdgcn_exp2f(x);
}

// float -> bf16 bits, round-to-nearest-even (finite inputs only)
static __device__ __forceinline__ unsigned short f2bf(float f) {
    unsigned int u = __float_as_uint(f);
    u = (u + 0x7FFFu + ((u >> 16) & 1u)) >> 16;
    return (unsigned short)u;
}
static __device__ __forceinline__ unsigned int pk2(float a, float b) {
    return (unsigned int)f2bf(a) | ((unsigned int)f2bf(b) << 16);
}

// ---------------------------------------------------------------------------
// Fragment-ordered workspace layouts (all bf16, per batch):
//   Q2[qtile(128)][f(2)][q(32)][hi(2)][e(8)]   : chan = f*16 + hi*8 + e, row = qtile*32+q
//   K2[kchunk(128)][f(2)][k(32)][hi(2)][e(8)]  : same, row = key
//   V2[kc(128)][w2(2)][ctg(8)][q(32)][hi(2)][e(8)] : c = ctg*32+q, key = kc*32+w2*16+hi*8+e
// A wave's 16B/lane fragment load covers one contiguous 1KB block -> fully
// coalesced (4 lines/instr instead of 64-line gathers; that gather was the
// R5/R7 ~170us floor).
// ---------------------------------------------------------------------------

// ---------------------------------------------------------------------------
// K1: 2x2 average pool. x[b][c][128][128] -> xp[b][c][64*64]
// ---------------------------------------------------------------------------
__global__ __launch_bounds__(256) void pool_kernel(const float* __restrict__ x,
                                                   float* __restrict__ xp) {
    int tid = blockIdx.x * 256 + threadIdx.x;      // B*C*NP threads
    int wp = tid & 63;
    int hp = (tid >> 6) & 63;
    int bc = tid >> 12;
    const float* src = x + (size_t)bc * (HH * WW) + (2 * hp) * WW + 2 * wp;
    float2 a = *(const float2*)(src);
    float2 b = *(const float2*)(src + WW);
    xp[tid] = 0.25f * (a.x + a.y + b.x + b.y);
}

// ---------------------------------------------------------------------------
// K2: fused QKV projection GEMM (fp32 math), bf16 outputs in fragment order.
// Q pre-scaled by log2(e) so flash softmax uses exp2 directly.
// ---------------------------------------------------------------------------
__global__ __launch_bounds__(256) void proj_kernel(const float* __restrict__ xp,
    const float* __restrict__ wq, const float* __restrict__ bq,
    const float* __restrict__ wk, const float* __restrict__ bk,
    const float* __restrict__ wv, const float* __restrict__ bv,
    unsigned short* __restrict__ qarr, unsigned short* __restrict__ karr,
    unsigned short* __restrict__ varr) {
    __shared__ float lx[32][64];    // [c][n]
    __shared__ float lwT[32][64];   // [c][o]
    int t = threadIdx.x;
    int ot = blockIdx.x % 5;
    int nt = (blockIdx.x / 5) & 63;
    int b  = blockIdx.x / 320;

    float acc[4][4];
    #pragma unroll
    for (int i = 0; i < 4; i++)
        #pragma unroll
        for (int j = 0; j < 4; j++) acc[i][j] = 0.f;

    int n0 = (t & 15) * 4;
    int o0 = (t >> 4) * 4;

    int o_l = t >> 2;               // 0..63 weight row
    int og  = ot * 64 + o_l;
    const float* wrow;
    if (og < 32)      wrow = wq + og * CC;
    else if (og < 64) wrow = wk + (og - 32) * CC;
    else              wrow = wv + (og - 64) * CC;
    int c8 = (t & 3) * 8;

    const float* xbase = xp + (size_t)b * CC * NP + nt * 64;
    int cl = t >> 3;                // 0..31
    int nl = (t & 7) * 8;

    for (int c0 = 0; c0 < 256; c0 += 32) {
        const float* xg = xbase + (size_t)(c0 + cl) * NP + nl;
        float4 v0 = *(const float4*)(xg);
        float4 v1 = *(const float4*)(xg + 4);
        float4 w0 = *(const float4*)(wrow + c0 + c8);
        float4 w1 = *(const float4*)(wrow + c0 + c8 + 4);
        __syncthreads();
        *(float4*)&lx[cl][nl]     = v0;
        *(float4*)&lx[cl][nl + 4] = v1;
        lwT[c8 + 0][o_l] = w0.x; lwT[c8 + 1][o_l] = w0.y;
        lwT[c8 + 2][o_l] = w0.z; lwT[c8 + 3][o_l] = w0.w;
        lwT[c8 + 4][o_l] = w1.x; lwT[c8 + 5][o_l] = w1.y;
        lwT[c8 + 6][o_l] = w1.z; lwT[c8 + 7][o_l] = w1.w;
        __syncthreads();
        #pragma unroll
        for (int cc = 0; cc < 32; cc += 4) {
            float4 xv[4], wv4[4];
            #pragma unroll
            for (int ci = 0; ci < 4; ci++) {
                xv[ci]  = *(const float4*)&lx[cc + ci][n0];
                wv4[ci] = *(const float4*)&lwT[cc + ci][o0];
            }
            #pragma unroll
            for (int ci = 0; ci < 4; ci++) {
                float xn[4] = {xv[ci].x, xv[ci].y, xv[ci].z, xv[ci].w};
                float wo[4] = {wv4[ci].x, wv4[ci].y, wv4[ci].z, wv4[ci].w};
                #pragma unroll
                for (int ni = 0; ni < 4; ni++)
                    #pragma unroll
                    for (int oi = 0; oi < 4; oi++)
                        acc[ni][oi] += xn[ni] * wo[oi];
            }
        }
    }

    float bias[4];
    #pragma unroll
    for (int oi = 0; oi < 4; oi++) {
        int o = ot * 64 + o0 + oi;
        bias[oi] = (o < 32) ? bq[o] : (o < 64) ? bk[o - 32] : bv[o - 64];
    }

    if (ot == 0) {
        // Q (o0<32) or K (o0>=32); wave-uniform since o0 = 16*(t>>6)+...
        bool isQ = (o0 < 32);
        int o2 = isQ ? o0 : (o0 - 32);
        int f  = o2 >> 4;
        int hi = (o2 >> 3) & 1;
        int e0 = o2 & 7;
        unsigned short* arr = (isQ ? qarr : karr) + (size_t)b * (NP * 32);
        float qs = isQ ? L2E : 1.0f;   // q pre-scaled for exp2 softmax
        #pragma unroll
        for (int ni = 0; ni < 4; ni++) {
            int n = nt * 64 + n0 + ni;
            ushort4 r;
            r.x = f2bf((acc[ni][0] + bias[0]) * qs);
            r.y = f2bf((acc[ni][1] + bias[1]) * qs);
            r.z = f2bf((acc[ni][2] + bias[2]) * qs);
            r.w = f2bf((acc[ni][3] + bias[3]) * qs);
            size_t idx = (((size_t)(n >> 5) * 2 + f) * 32 + (n & 31)) * 16 + hi * 8 + e0;
            *(ushort4*)(arr + idx) = r;
        }
    } else {
        int n0g = nt * 64 + n0;
        int kc = n0g >> 5, w2 = (n0g >> 4) & 1, hi = (n0g >> 3) & 1, e0 = n0g & 7;
        unsigned short* vb = varr + (size_t)b * (CC * NP);
        #pragma unroll
        for (int oi = 0; oi < 4; oi++) {
            int c = ot * 64 + o0 + oi - 64;
            int ctg = c >> 5, cq = c & 31;
            ushort4 r;
            r.x = f2bf(acc[0][oi] + bias[oi]);
            r.y = f2bf(acc[1][oi] + bias[oi]);
            r.z = f2bf(acc[2][oi] + bias[oi]);
            r.w = f2bf(acc[3][oi] + bias[oi]);
            size_t idx = ((((size_t)kc * 2 + w2) * 8 + ctg) * 32 + cq) * 16 + hi * 8 + e0;
            *(ushort4*)(vb + idx) = r;
        }
    }
}

// ---------------------------------------------------------------------------
// K3: swapped-operand 32x32 MFMA flash attention, 2D wave split (key x4, ch x2),
// fragment-ordered inputs (all loads 1KB-contiguous per wave).
// 512-thread block = 8 waves; wave w: ch = w&1 (128 channels), ks = w>>1
// (1024 keys). Split-K combine per channel group; ks==0 writes.
//
// QK^T (swapped): S^T = mfma_32x32x16(A=K, B=Q).
//   D layout (m74/m101): col=lane&31 = q; row=(r&3)+8*(r>>2)+4*(lane>>5) = key.
// PV: out[c][q] = mfma(A=V^T, B=P); P B-frag built in-register via pk2+shfl.
// ---------------------------------------------------------------------------
__global__ __launch_bounds__(512, 4) void flash32_kernel(const unsigned short* __restrict__ qarr,
                                                         const unsigned short* __restrict__ karr,
                                                         const unsigned short* __restrict__ varr,
                                                         float* __restrict__ att) {
    __shared__ float cacc[2][64][68];  // combine: per ch-group, 64 lanes x 64 f32
    __shared__ float cml[2][64][2];    // combine: m, l per lane
    int t    = threadIdx.x;
    int lane = t & 63;
    int w    = t >> 6;                 // 0..7
    int ch   = w & 1;                  // channel half
    int ks   = w >> 1;                 // key quarter
    int j    = blockIdx.x;
    int b    = j & 3;                  // batch -> XCD pinning
    int qt   = j >> 2;                 // 0..127 q-tile (32 rows)

    const unsigned short* qb2 = qarr + (size_t)b * (NP * 32);
    const unsigned short* kb2 = karr + (size_t)b * (NP * 32);
    const unsigned short* vb2 = varr + (size_t)b * (CC * NP);

    int q  = lane & 31;
    int hi = lane >> 5;
    int lq16 = (q * 2 + hi) * 8;       // lane's 16B slot within a 1KB fragment block

    // Q B-frags (held whole kernel): chans f*16 + hi*8 + e of row qt*32+q
    bf16x8 qf0 = *(const bf16x8*)(qb2 + (size_t)(qt * 2 + 0) * 512 + lq16);
    bf16x8 qf1 = *(const bf16x8*)(qb2 + (size_t)(qt * 2 + 1) * 512 + lq16);

    f32x16 acc[4];
    #pragma unroll
    for (int ct = 0; ct < 4; ct++)
        #pragma unroll
        for (int r = 0; r < 16; r++) acc[ct][r] = 0.f;
    float mrun = -3.0e38f, lrun = 0.f;

    const f32x16 z16 = {0.f,0.f,0.f,0.f,0.f,0.f,0.f,0.f,0.f,0.f,0.f,0.f,0.f,0.f,0.f,0.f};

    for (int kci = 0; kci < 32; ++kci) {
        int kcidx = ks * 32 + kci;     // key chunk (32 keys)

        // ---- QK^T swapped: A=K (row=key), B=Q -> S^T (log2 units)
        const unsigned short* kcp = kb2 + (size_t)kcidx * 1024 + lq16;
        bf16x8 kf0 = *(const bf16x8*)(kcp);
        bf16x8 kf1 = *(const bf16x8*)(kcp + 512);
        f32x16 s = __builtin_amdgcn_mfma_f32_32x32x16_bf16(kf0, qf0, z16, 0, 0, 0);
        s = __builtin_amdgcn_mfma_f32_32x32x16_bf16(kf1, qf1, s, 0, 0, 0);

        // ---- in-lane max over 16 keys + 1 cross-half swap
        float m01 = fmaxf(s[0], s[1]),   m23 = fmaxf(s[2], s[3]);
        float m45 = fmaxf(s[4], s[5]),   m67 = fmaxf(s[6], s[7]);
        float m89 = fmaxf(s[8], s[9]),   mab = fmaxf(s[10], s[11]);
        float mcd = fmaxf(s[12], s[13]), mef = fmaxf(s[14], s[15]);
        float mx = fmaxf(fmaxf(fmaxf(m01, m23), fmaxf(m45, m67)),
                         fmaxf(fmaxf(m89, mab), fmaxf(mcd, mef)));
        mx = fmaxf(mx, __shfl_xor(mx, 32, 64));

        // ---- defer-max (T13, log2 domain): rescale only when max grew by > ~11.5
        if (!__all(mx - mrun <= 11.5f)) {
            float mn = fmaxf(mrun, mx);
            float sc = exp2fast(mrun - mn);
            mrun = mn;
            lrun *= sc;
            #pragma unroll
            for (int ct = 0; ct < 4; ct++)
                #pragma unroll
                for (int r = 0; r < 16; r++) acc[ct][r] *= sc;
        }

        // ---- P = exp2(S^T - m): pack pairs as we go
        unsigned int pkr[8];
        float ss = 0.f;
        #pragma unroll
        for (int r2 = 0; r2 < 8; r2++) {
            float p0 = exp2fast(s[2 * r2]     - mrun);
            float p1 = exp2fast(s[2 * r2 + 1] - mrun);
            ss += p0 + p1;
            pkr[r2] = pk2(p0, p1);
        }
        ss += __shfl_xor(ss, 32, 64);
        lrun += ss;

        // ---- PV: per 16-key window, build P B-frag in-register, 4 c-tiles
        const unsigned short* vcp = vb2 + ((size_t)kcidx * 16 + ch * 4) * 512 + lq16;
        #pragma unroll
        for (int w2 = 0; w2 < 2; w2++) {
            unsigned int a0 = pkr[4 * w2 + 0];
            unsigned int a1 = pkr[4 * w2 + 1];
            unsigned int c0 = pkr[4 * w2 + 2];
            unsigned int c1 = pkr[4 * w2 + 3];
            unsigned int sa0 = __shfl_xor(a0, 32, 64);
            unsigned int sa1 = __shfl_xor(a1, 32, 64);
            unsigned int sc0 = __shfl_xor(c0, 32, 64);
            unsigned int sc1 = __shfl_xor(c1, 32, 64);
            u32x4 fr;
            if (hi == 0) { fr[0] = a0;  fr[1] = a1;  fr[2] = sa0; fr[3] = sa1; }
            else         { fr[0] = sc0; fr[1] = sc1; fr[2] = c0;  fr[3] = c1;  }
            bf16x8 pf = __builtin_bit_cast(bf16x8, fr);
            #pragma unroll
            for (int ct = 0; ct < 4; ct++) {
                bf16x8 vf = *(const bf16x8*)(vcp + (size_t)(w2 * 8 + ct) * 512);
                acc[ct] = __builtin_amdgcn_mfma_f32_32x32x16_bf16(vf, pf, acc[ct], 0, 0, 0);
            }
        }
    }

    // ---- split-K combine within each channel group (ks 3,2,1 -> ks 0)
    for (int sIdx = 3; sIdx >= 1; --sIdx) {
        if (ks == sIdx) {
            #pragma unroll
            for (int ct = 0; ct < 4; ct++)
                #pragma unroll
                for (int rr = 0; rr < 4; rr++) {
                    float4 v4 = {acc[ct][rr*4+0], acc[ct][rr*4+1], acc[ct][rr*4+2], acc[ct][rr*4+3]};
                    *(float4*)&cacc[ch][lane][ct * 16 + rr * 4] = v4;
                }
            cml[ch][lane][0] = mrun; cml[ch][lane][1] = lrun;
        }
        __syncthreads();
        if (ks == 0) {
            float mo = cml[ch][lane][0];
            float lo = cml[ch][lane][1];
            float mn = fmaxf(mrun, mo);
            float e0 = exp2fast(mrun - mn);
            float e1 = exp2fast(mo - mn);
            mrun = mn;
            lrun = lrun * e0 + lo * e1;
            #pragma unroll
            for (int ct = 0; ct < 4; ct++)
                #pragma unroll
                for (int r = 0; r < 16; r++)
                    acc[ct][r] = acc[ct][r] * e0 + cacc[ch][lane][ct * 16 + r] * e1;
        }
        __syncthreads();
    }

    if (ks == 0) {
        float inv = 1.0f / lrun;
        #pragma unroll
        for (int ct = 0; ct < 4; ct++)
            #pragma unroll
            for (int r = 0; r < 16; r++) {
                int c = ch * 128 + ct * 32 + (r & 3) + 8 * (r >> 2) + 4 * hi;
                att[((size_t)b * CC + c) * NP + qt * 32 + q] = acc[ct][r] * inv;
            }
    }
}

// ---------------------------------------------------------------------------
// K4: bilinear x2 upsample (half-pixel, edge clamp) + gamma * up + x
// ---------------------------------------------------------------------------
__global__ __launch_bounds__(256) void upsample_kernel(const float* __restrict__ att,
                                                       const float* __restrict__ x,
                                                       const float* __restrict__ gamma,
                                                       float* __restrict__ out) {
    int tid = blockIdx.x * 256 + threadIdx.x;    // B*C*H*W
    int w = tid & 127;
    int h = (tid >> 7) & 127;
    int bc = tid >> 14;
    float g = gamma[0];
    float sh = 0.5f * h - 0.25f;
    float sw = 0.5f * w - 0.25f;
    float fhf = floorf(sh), fwf = floorf(sw);
    float th = sh - fhf, tw = sw - fwf;
    int ih = (int)fhf, iw = (int)fwf;
    int ih0 = ih < 0 ? 0 : ih;
    int ih1 = ih + 1 > 63 ? 63 : ih + 1;
    int iw0 = iw < 0 ? 0 : iw;
    int iw1 = iw + 1 > 63 ? 63 : iw + 1;
    const float* a = att + (size_t)bc * NP;
    float v00 = a[ih0 * 64 + iw0], v01 = a[ih0 * 64 + iw1];
    float v10 = a[ih1 * 64 + iw0], v11 = a[ih1 * 64 + iw1];
    float top = v00 + tw * (v01 - v00);
    float bot = v10 + tw * (v11 - v10);
    float up  = top + th * (bot - top);
    out[tid] = g * up + x[tid];
}

// ---------------------------------------------------------------------------
extern "C" void kernel_launch(void* const* d_in, const int* in_sizes, int n_in,
                              void* d_out, int out_size, void* d_ws, size_t ws_size,
                              hipStream_t stream) {
    (void)in_sizes; (void)n_in; (void)out_size; (void)ws_size;
    const float* x     = (const float*)d_in[0];
    const float* wq    = (const float*)d_in[1];
    const float* bq    = (const float*)d_in[2];
    const float* wk    = (const float*)d_in[3];
    const float* bk    = (const float*)d_in[4];
    const float* wv    = (const float*)d_in[5];
    const float* bv    = (const float*)d_in[6];
    const float* gamma = (const float*)d_in[7];
    float* out = (float*)d_out;
    float* ws  = (float*)d_ws;

    float*          xp   = ws;                                 // 4,194,304 f32 (16 MB)
    unsigned short* qarr = (unsigned short*)(ws + 4194304);    // 4*NP*32 = 524,288 bf16 (1 MB)
    unsigned short* karr = qarr + 524288;                      // 524,288 bf16 (1 MB)
    unsigned short* varr = karr + 524288;                      // 4*CC*NP = 4,194,304 bf16 (8 MB)
    float*          att  = (float*)(varr + 4194304);           // 4,194,304 f32 (16 MB)

    pool_kernel<<<16384, 256, 0, stream>>>(x, xp);
    proj_kernel<<<1280, 256, 0, stream>>>(xp, wq, bq, wk, bk, wv, bv, qarr, karr, varr);
    flash32_kernel<<<512, 512, 0, stream>>>(qarr, karr, varr, att);
    upsample_kernel<<<65536, 256, 0, stream>>>(att, x, gamma, out);
}